// Round 13
// baseline (138.245 us; speedup 1.0000x reference)
//
#include <hip/hip_runtime.h>

// N=1, L=512, F=128, C=64, H=12, QK=32, Vd=32, Pq=8, Pv=8
#define PCOLS 2016

constexpr float INV_SQRT_QK = 0.17677669529663687f;  // 1/sqrt(32)
constexpr float S3          = 0.57735026918962576f;  // sqrt(1/3)

#define FMA4(acc, s, b) { acc.x += (s)*(b).x; acc.y += (s)*(b).y; acc.z += (s)*(b).z; acc.w += (s)*(b).w; }
#define ADD4(acc, b)    { acc.x += (b).x; acc.y += (b).y; acc.z += (b).z; acc.w += (b).w; }

// ---------------- K1: all projections as one tiled GEMM (LDS-staged W) ----------------
__global__ __launch_bounds__(384) void k1_gemm(
    const float* __restrict__ x,
    const float* __restrict__ Wq, const float* __restrict__ Wk,
    const float* __restrict__ Wqp, const float* __restrict__ Wkp,
    const float* __restrict__ Wv, const float* __restrict__ Wvp,
    float* __restrict__ proj) {
  int bt = blockIdx.x;
  int it = bt / 21, ot = bt % 21;
  int i0 = it * 64;
  int tid = threadIdx.x;
  __shared__ float xs[64 * 128];
  __shared__ float ws[128 * 96];
  const float* Wsec; int lofs, width;
  if (ot < 4)       { Wsec = Wq;  lofs = ot * 96;        width = 384; }
  else if (ot < 8)  { Wsec = Wk;  lofs = (ot - 4) * 96;  width = 384; }
  else if (ot < 11) { Wsec = Wqp; lofs = (ot - 8) * 96;  width = 288; }
  else if (ot < 14) { Wsec = Wkp; lofs = (ot - 11) * 96; width = 288; }
  else if (ot < 18) { Wsec = Wv;  lofs = (ot - 14) * 96; width = 384; }
  else              { Wsec = Wvp; lofs = (ot - 18) * 96; width = 288; }
  for (int g = tid; g < 2048; g += 384)
    *(float4*)(xs + (g >> 5) * 128 + (g & 31) * 4) =
      *(const float4*)(x + (size_t)(i0 + (g >> 5)) * 128 + (g & 31) * 4);
  for (int g = tid; g < 3072; g += 384) {
    int r = g / 24, u = g % 24;
    *(float4*)(ws + r * 96 + u * 4) = *(const float4*)(Wsec + (size_t)r * width + lofs + u * 4);
  }
  __syncthreads();
  int cg = tid % 24, tr = tid / 24;
  float4 acc0 = {0,0,0,0}, acc1 = {0,0,0,0}, acc2 = {0,0,0,0}, acc3 = {0,0,0,0};
  const float* x0 = xs + (tr * 4 + 0) * 128;
  const float* x1 = xs + (tr * 4 + 1) * 128;
  const float* x2 = xs + (tr * 4 + 2) * 128;
  const float* x3 = xs + (tr * 4 + 3) * 128;
  #pragma unroll 4
  for (int k = 0; k < 128; ++k) {
    float4 w = *(const float4*)(ws + k * 96 + cg * 4);
    FMA4(acc0, x0[k], w); FMA4(acc1, x1[k], w);
    FMA4(acc2, x2[k], w); FMA4(acc3, x3[k], w);
  }
  int gc = ot * 96 + cg * 4;
  *(float4*)(proj + (size_t)(i0 + tr * 4 + 0) * PCOLS + gc) = acc0;
  *(float4*)(proj + (size_t)(i0 + tr * 4 + 1) * PCOLS + gc) = acc1;
  *(float4*)(proj + (size_t)(i0 + tr * 4 + 2) * PCOLS + gc) = acc2;
  *(float4*)(proj + (size_t)(i0 + tr * 4 + 3) * PCOLS + gc) = acc3;
}

// ---------------- K1b: l2g transform + compact operands Ac / BcT / Vc / a2 / b2 ----------------
__global__ __launch_bounds__(256) void k1b_prep(
    const float* __restrict__ Rg, const float* __restrict__ tg, const float* __restrict__ sc,
    const float* __restrict__ proj, float* __restrict__ Ac, float* __restrict__ BcT,
    float* __restrict__ Vc, float* __restrict__ a2, float* __restrict__ b2) {
  int j = blockIdx.x, tid = threadIdx.x;
  __shared__ float qk[1344];
  __shared__ float vls[384];
  __shared__ float vps[288], Rs[9], ts[3], cf[12];
  const float* pr = proj + (size_t)j * PCOLS;
  const float4* pr4 = (const float4*)pr;
  for (int g = tid; g < 336; g += 256) ((float4*)qk)[g] = pr4[g];
  for (int g = tid; g < 96; g += 256) ((float4*)vls)[g] = pr4[336 + g];
  for (int g = tid; g < 72; g += 256) ((float4*)vps)[g] = pr4[432 + g];
  if (tid < 9) Rs[tid] = Rg[j * 9 + tid];
  else if (tid < 12) ts[tid - 9] = tg[j * 3 + tid - 9];
  else if (tid < 24) cf[tid - 12] = -log1pf(__expf(sc[tid - 12])) * (1.0f / 12.0f);
  __syncthreads();
  for (int p = tid; p < 288; p += 256) {
    int sec = p / 96, m = p % 96;
    float* P = (sec == 0) ? qk + 768 : (sec == 1) ? qk + 1056 : vps;
    float* pp = P + m * 3;
    float p0 = pp[0], p1 = pp[1], p2 = pp[2];
    pp[0] = Rs[0]*p0 + Rs[1]*p1 + Rs[2]*p2 + ts[0];
    pp[1] = Rs[3]*p0 + Rs[4]*p1 + Rs[5]*p2 + ts[1];
    pp[2] = Rs[6]*p0 + Rs[7]*p1 + Rs[8]*p2 + ts[2];
  }
  __syncthreads();
  if (tid < 24) {
    int h = tid % 12;
    const float* s = (tid < 12) ? qk + 768 + h * 24 : qk + 1056 + h * 24;
    float a = 0.f;
    #pragma unroll
    for (int d = 0; d < 24; ++d) a += s[d] * s[d];
    float val = S3 * cf[h] * a;
    if (tid < 12) a2[h * 512 + j] = val; else b2[h * 512 + j] = val;
  }
  float s1 = S3 * INV_SQRT_QK;
  for (int o = tid; o < 672; o += 256) {
    int h = o / 56, d = o % 56;
    float s2 = -2.0f * S3 * cf[h];
    float aval = (d < 32) ? qk[h * 32 + d] * s1 : qk[768 + h * 24 + (d - 32)] * s2;
    float bval = (d < 32) ? qk[384 + h * 32 + d] : qk[1056 + h * 24 + (d - 32)];
    float vval = (d < 32) ? vls[h * 32 + d]      : vps[h * 24 + (d - 32)];
    Ac[((size_t)h * 512 + j) * 56 + d] = aval;
    BcT[((size_t)h * 56 + d) * 512 + j] = bval;
    Vc[((size_t)h * 512 + j) * 56 + d] = vval;
  }
}

// ---------------- K2l: node+spatial logits GEMM (K=56) -> lgb[h][i][j] ----------------
__global__ __launch_bounds__(512) void k2l_logits(
    const float* __restrict__ Ac, const float* __restrict__ BcT,
    const float* __restrict__ a2, const float* __restrict__ b2,
    float* __restrict__ lgb) {
  int blk = blockIdx.x;
  int h = blk >> 5, i0 = (blk & 31) * 16;
  int tid = threadIdx.x;
  __shared__ float At[16 * 60];
  __shared__ float BtT[56 * 132];
  __shared__ float b2s[512];
  __shared__ float a2s[16];
  for (int g = tid; g < 224; g += 512) {
    int row = g / 14, u = g % 14;
    *(float4*)(At + row * 60 + u * 4) =
      *(const float4*)(Ac + ((size_t)h * 512 + i0 + row) * 56 + u * 4);
  }
  if (tid < 128) ((float4*)b2s)[tid] = ((const float4*)(b2 + h * 512))[tid];
  if (tid >= 128 && tid < 144) a2s[tid - 128] = a2[h * 512 + i0 + tid - 128];
  int ti = tid >> 6, tj = tid & 63;
  int r0 = 2 * ti;
  const size_t lbase = (size_t)h * 262144;
  for (int jt = 0; jt < 4; ++jt) {
    int j0 = jt * 128;
    __syncthreads();
    for (int g = tid; g < 1792; g += 512) {
      int k = g >> 5, c4 = g & 31;
      *(float4*)(BtT + k * 132 + c4 * 4) =
        *(const float4*)(BcT + ((size_t)h * 56 + k) * 512 + j0 + c4 * 4);
    }
    __syncthreads();
    float a00 = 0.f, a01 = 0.f, a10 = 0.f, a11 = 0.f;
    const float* At0 = At + r0 * 60;
    #pragma unroll 8
    for (int k = 0; k < 56; ++k) {
      float a0 = At0[k], a1 = At0[60 + k];
      float2 b = *(const float2*)(BtT + k * 132 + 2 * tj);
      a00 += a0 * b.x; a01 += a0 * b.y;
      a10 += a1 * b.x; a11 += a1 * b.y;
    }
    int c0 = j0 + 2 * tj;
    float bb0 = b2s[c0], bb1 = b2s[c0 + 1];
    *(float2*)(lgb + lbase + (size_t)(i0 + r0) * 512 + c0) =
      make_float2(a00 + a2s[r0] + bb0, a01 + a2s[r0] + bb1);
    *(float2*)(lgb + lbase + (size_t)(i0 + r0 + 1) * 512 + c0) =
      make_float2(a10 + a2s[r0 + 1] + bb0, a11 + a2s[r0 + 1] + bb1);
  }
}

// ---------------- KZ v3: pair logits (broadcast-Wpair, quad c-split) + softmax + p2n ----------------
// grid 512 (one i per block), 512 threads. Pass A: thread (r=tid>>2, q=tid&3);
// 12 acc + 12 weight temps only -> no scratch. Wpair in LDS quarter-padded (264-word
// stride => disjoint banks for the 4 broadcast groups).
__global__ __launch_bounds__(512) void kz_fused(
    const float* __restrict__ z, const float* __restrict__ Wpair,
    const float* __restrict__ lgb,
    float* __restrict__ alphab, float* __restrict__ featb) {
  int i = blockIdx.x;
  int tid = threadIdx.x;
  int lane = tid & 63, wv = tid >> 6;
  __shared__ float lg[12 * 516];     // 24.8 KB: pair logits -> alpha
  __shared__ float zt[128 * 68];     // 34.8 KB (pass A: 128 rows; pass B: 64 rows)
  __shared__ float wp2[4 * 264];     // 4.2 KB: Wpair [q][cc][h pad 16], quarter stride 264
  __shared__ float4 part[192];       // 3 KB (pass B)
  // stage Wpair: c = g/12 -> (q = c>>4, cc = c&15), h = g%12
  for (int g = tid; g < 768; g += 512) {
    int c = g / 12, h = g % 12;
    wp2[(c >> 4) * 264 + (c & 15) * 16 + h] = Wpair[g];
  }
  int r = tid >> 2, q = tid & 3;     // row in tile, c-quarter (16 c each)
  const float* wq = wp2 + q * 264;
  // --- pass A: 4 tiles x 128 rows ---
  for (int t = 0; t < 4; ++t) {
    __syncthreads();   // prior compute done before restaging
    for (int g = tid; g < 2048; g += 512) {
      int row = g >> 4, cc = g & 15;
      *(float4*)(zt + row * 68 + cc * 4) =
        *(const float4*)(z + ((size_t)i * 512 + t * 128 + row) * 64 + cc * 4);
    }
    __syncthreads();
    float acc[12];
    #pragma unroll
    for (int h = 0; h < 12; ++h) acc[h] = 0.f;
    const float* zr = zt + r * 68 + q * 16;
    #pragma unroll
    for (int cc = 0; cc < 16; ++cc) {
      float zz = zr[cc];
      const float* wr = wq + cc * 16;
      float4 w0 = *(const float4*)(wr);
      float4 w1 = *(const float4*)(wr + 4);
      float4 w2 = *(const float4*)(wr + 8);
      acc[0] += zz * w0.x; acc[1] += zz * w0.y; acc[2]  += zz * w0.z; acc[3]  += zz * w0.w;
      acc[4] += zz * w1.x; acc[5] += zz * w1.y; acc[6]  += zz * w1.z; acc[7]  += zz * w1.w;
      acc[8] += zz * w2.x; acc[9] += zz * w2.y; acc[10] += zz * w2.z; acc[11] += zz * w2.w;
    }
    #pragma unroll
    for (int h = 0; h < 12; ++h) {
      float v = acc[h];
      v += __shfl_xor(v, 1);
      v += __shfl_xor(v, 2);
      if (q == 0) lg[h * 516 + t * 128 + r] = v * S3;
    }
  }
  __syncthreads();
  // --- softmax per head (wave-parallel), fusing lgb add; alpha -> LDS + global ---
  for (int h = wv; h < 12; h += 8) {
    const float* lr = lgb + (size_t)h * 262144 + (size_t)i * 512;
    float v[8];
    float m = -1e30f;
    #pragma unroll
    for (int u = 0; u < 8; ++u) {
      v[u] = lg[h * 516 + u * 64 + lane] + lr[u * 64 + lane];
      m = fmaxf(m, v[u]);
    }
    #pragma unroll
    for (int s = 32; s > 0; s >>= 1) m = fmaxf(m, __shfl_xor(m, s));
    float ssum = 0.f;
    #pragma unroll
    for (int u = 0; u < 8; ++u) { v[u] = __expf(v[u] - m); ssum += v[u]; }
    #pragma unroll
    for (int s = 32; s > 0; s >>= 1) ssum += __shfl_xor(ssum, s);
    float inv = 1.0f / ssum;
    float* ar = alphab + (size_t)h * 262144 + (size_t)i * 512;
    #pragma unroll
    for (int u = 0; u < 8; ++u) {
      float a = v[u] * inv;
      lg[h * 516 + u * 64 + lane] = a;
      ar[u * 64 + lane] = a;
    }
  }
  __syncthreads();
  // --- pass B: feat_p2n = alpha @ z[i], z re-read (L2/L3-hot), k-split 2 ---
  int h3 = tid >> 5, c4 = (tid & 31) >> 1, ks = tid & 1;   // valid tid < 384
  float4 acc4 = {0, 0, 0, 0};
  for (int it = 0; it < 8; ++it) {
    __syncthreads();
    for (int g = tid; g < 1024; g += 512) {
      int row = g >> 4, cc = g & 15;
      *(float4*)(zt + row * 68 + cc * 4) =
        *(const float4*)(z + ((size_t)i * 512 + it * 64 + row) * 64 + cc * 4);
    }
    __syncthreads();
    if (tid < 384) {
      const float* ar2 = lg + h3 * 516 + it * 64 + ks * 32;
      const float* zb = zt + (ks * 32) * 68 + c4 * 4;
      #pragma unroll
      for (int kk = 0; kk < 32; kk += 4) {
        float4 a4 = *(const float4*)(ar2 + kk);
        float4 b0 = *(const float4*)(zb + (kk + 0) * 68);
        float4 b1 = *(const float4*)(zb + (kk + 1) * 68);
        float4 b2v = *(const float4*)(zb + (kk + 2) * 68);
        float4 b3 = *(const float4*)(zb + (kk + 3) * 68);
        FMA4(acc4, a4.x, b0); FMA4(acc4, a4.y, b1);
        FMA4(acc4, a4.z, b2v); FMA4(acc4, a4.w, b3);
      }
    }
  }
  __syncthreads();
  if (tid < 384 && ks == 1) part[h3 * 16 + c4] = acc4;
  __syncthreads();
  if (tid < 384 && ks == 0) {
    float4 s = part[h3 * 16 + c4];
    ADD4(acc4, s);
    *(float4*)(featb + (size_t)i * 1440 + h3 * 64 + c4 * 4) = acc4;
  }
}

// ---------------- K3b: node/vp aggregation + g2l (alpha from global, compact Vc) ----------------
__global__ __launch_bounds__(512) void k3b_nodevp(
    const float* __restrict__ alphab, const float* __restrict__ Vc,
    const float* __restrict__ Rg, const float* __restrict__ tg,
    float* __restrict__ featb) {
  int blk = blockIdx.x;
  int h = blk >> 5, i0 = (blk & 31) * 16;
  int tid = threadIdx.x;
  __shared__ float als[16 * 516];
  __shared__ float Bt2[2 * 64 * 60];
  __shared__ float4 part4[448];
  __shared__ float ag[16 * 24];
  for (int g = tid; g < 2048; g += 512) {
    int row = g >> 7, c4 = g & 127;
    *(float4*)(als + row * 516 + c4 * 4) =
      *(const float4*)(alphab + (size_t)h * 262144 + (size_t)(i0 + row) * 512 + c4 * 4);
  }
  int half = tid / 224, rem = tid % 224;
  int rg = rem / 14, cgp = rem % 14;
  int c0p = cgp * 4;
  float4 acc4 = {0, 0, 0, 0};
  for (int tt = 0; tt < 4; ++tt) {
    __syncthreads();
    for (int g = tid; g < 1792; g += 512) {
      int hh = g / 896, gg = g % 896;
      int row = gg / 14, u = gg % 14;
      *(float4*)(Bt2 + hh * 3840 + row * 60 + u * 4) =
        *(const float4*)(Vc + ((size_t)h * 512 + (tt + 4 * hh) * 64 + row) * 56 + u * 4);
    }
    __syncthreads();
    if (tid < 448) {
      const float* arow = als + rg * 516 + (tt + 4 * half) * 64;
      const float* bt = Bt2 + half * 3840;
      #pragma unroll 8
      for (int kk = 0; kk < 64; ++kk) {
        float a = arow[kk];
        float4 b = *(const float4*)(bt + kk * 60 + c0p);
        FMA4(acc4, a, b);
      }
    }
  }
  __syncthreads();
  if (tid < 448) part4[half * 224 + rg * 14 + cgp] = acc4;
  __syncthreads();
  if (tid < 224) {
    float4 s = part4[rem];
    float4 s2 = part4[224 + rem];
    ADD4(s, s2);
    if (c0p < 32) {
      *(float4*)(&featb[(size_t)(i0 + rg) * 1440 + 768 + h * 32 + c0p]) = s;
    } else {
      int cc = c0p - 32;
      ag[rg * 24 + cc + 0] = s.x; ag[rg * 24 + cc + 1] = s.y;
      ag[rg * 24 + cc + 2] = s.z; ag[rg * 24 + cc + 3] = s.w;
    }
  }
  __syncthreads();
  if (tid < 128) {
    int row = tid >> 3, p = tid & 7;
    const float* R  = Rg + (size_t)(i0 + row) * 9;
    const float* tt = tg + (size_t)(i0 + row) * 3;
    float d0 = ag[row * 24 + p * 3 + 0] - tt[0];
    float d1 = ag[row * 24 + p * 3 + 1] - tt[1];
    float d2 = ag[row * 24 + p * 3 + 2] - tt[2];
    float* oo = featb + (size_t)(i0 + row) * 1440 + 1152 + h * 24 + p * 3;
    oo[0] = R[0]*d0 + R[3]*d1 + R[6]*d2;
    oo[1] = R[1]*d0 + R[4]*d1 + R[7]*d2;
    oo[2] = R[2]*d0 + R[5]*d1 + R[8]*d2;
  }
}

// ---------------- K4: Wo GEMM + LN1 + MLP + LN2 ----------------
__global__ __launch_bounds__(512) void k4_mlp(
    const float* __restrict__ featb, const float* __restrict__ x,
    const float* __restrict__ Wo, const float* __restrict__ bo,
    const float* __restrict__ ln1s, const float* __restrict__ ln1o,
    const float* __restrict__ W1, const float* __restrict__ b1,
    const float* __restrict__ W2, const float* __restrict__ b2,
    const float* __restrict__ W3, const float* __restrict__ b3,
    const float* __restrict__ ln2s, const float* __restrict__ ln2o,
    float* __restrict__ out) {
  int i0 = blockIdx.x * 2;
  int tid = threadIdx.x;
  __shared__ float fs[2 * 1440];
  __shared__ float4 part4[16][2][32];
  __shared__ float stgA[2][128], stgB[2][128], stgC[2][128];
  for (int g = tid; g < 720; g += 512)
    ((float4*)fs)[g] = ((const float4*)(featb + (size_t)i0 * 1440))[g];
  __syncthreads();
  int q = tid >> 5, cg = tid & 31;
  {
    float4 a0 = {0,0,0,0}, a1 = {0,0,0,0};
    int cb = q * 90;
    const float* f0 = fs + cb, *f1 = fs + 1440 + cb;
    #pragma unroll 6
    for (int c = 0; c < 90; ++c) {
      float4 w = *((const float4*)(Wo + (size_t)(cb + c) * 128) + cg);
      FMA4(a0, f0[c], w);
      FMA4(a1, f1[c], w);
    }
    part4[q][0][cg] = a0;
    part4[q][1][cg] = a1;
  }
  __syncthreads();
  if (tid < 64) {
    int rr = tid >> 5, c = tid & 31;
    float4 s = part4[0][rr][c];
    #pragma unroll
    for (int k = 1; k < 16; ++k) ADD4(s, part4[k][rr][c]);
    float4 bo4 = ((const float4*)bo)[c];
    float4 xr4 = ((const float4*)(x + (size_t)(i0 + rr) * 128))[c];
    s.x += bo4.x + xr4.x; s.y += bo4.y + xr4.y; s.z += bo4.z + xr4.z; s.w += bo4.w + xr4.w;
    ((float4*)stgA[rr])[c] = s;
  }
  __syncthreads();
  int q2 = tid >> 7, col = tid & 127, rr = q2 & 1;
  float x1;
  {
    float y = stgA[rr][col];
    float s1 = 0.f, s2 = 0.f;
    #pragma unroll 8
    for (int c4 = 0; c4 < 32; ++c4) {
      float4 v = ((const float4*)stgA[rr])[c4];
      s1 += v.x + v.y + v.z + v.w;
      s2 += v.x*v.x + v.y*v.y + v.z*v.z + v.w*v.w;
    }
    float mu = s1 * (1.f / 128.f);
    float var = s2 * (1.f / 128.f) - mu * mu;
    x1 = (y - mu) * rsqrtf(var + 1e-5f) * ln1s[col] + ln1o[col];
  }
  __syncthreads();
  stgB[rr][col] = x1;
  __syncthreads();
  int sub = tid >> 5, rr1 = sub & 1, kq = sub >> 1;
  {
    float4 aa = {0,0,0,0};
    int c0 = kq * 16;
    #pragma unroll
    for (int c = 0; c < 16; ++c) {
      float4 w = *((const float4*)(W1 + (size_t)(c0 + c) * 128) + cg);
      FMA4(aa, stgB[rr1][c0 + c], w);
    }
    part4[sub][0][cg] = aa;
  }
  __syncthreads();
  if (tid < 64) {
    int r2 = tid >> 5, c = tid & 31;
    float4 s = part4[r2][0][c];
    #pragma unroll
    for (int k = 1; k < 8; ++k) ADD4(s, part4[k * 2 + r2][0][c]);
    float4 b4 = ((const float4*)b1)[c];
    s.x = fmaxf(s.x + b4.x, 0.f); s.y = fmaxf(s.y + b4.y, 0.f);
    s.z = fmaxf(s.z + b4.z, 0.f); s.w = fmaxf(s.w + b4.w, 0.f);
    ((float4*)stgA[r2])[c] = s;
  }
  __syncthreads();
  {
    float4 aa = {0,0,0,0};
    int c0 = kq * 16;
    #pragma unroll
    for (int c = 0; c < 16; ++c) {
      float4 w = *((const float4*)(W2 + (size_t)(c0 + c) * 128) + cg);
      FMA4(aa, stgA[rr1][c0 + c], w);
    }
    part4[sub][0][cg] = aa;
  }
  __syncthreads();
  if (tid < 64) {
    int r2 = tid >> 5, c = tid & 31;
    float4 s = part4[r2][0][c];
    #pragma unroll
    for (int k = 1; k < 8; ++k) ADD4(s, part4[k * 2 + r2][0][c]);
    float4 b4 = ((const float4*)b2)[c];
    s.x = fmaxf(s.x + b4.x, 0.f); s.y = fmaxf(s.y + b4.y, 0.f);
    s.z = fmaxf(s.z + b4.z, 0.f); s.w = fmaxf(s.w + b4.w, 0.f);
    ((float4*)stgC[r2])[c] = s;
  }
  __syncthreads();
  {
    float4 aa = {0,0,0,0};
    int c0 = kq * 16;
    #pragma unroll
    for (int c = 0; c < 16; ++c) {
      float4 w = *((const float4*)(W3 + (size_t)(c0 + c) * 128) + cg);
      FMA4(aa, stgC[rr1][c0 + c], w);
    }
    part4[sub][0][cg] = aa;
  }
  __syncthreads();
  if (tid < 64) {
    int r2 = tid >> 5, c = tid & 31;
    float4 s = part4[r2][0][c];
    #pragma unroll
    for (int k = 1; k < 8; ++k) ADD4(s, part4[k * 2 + r2][0][c]);
    float4 b4 = ((const float4*)b3)[c];
    s.x += b4.x; s.y += b4.y; s.z += b4.z; s.w += b4.w;
    ((float4*)stgA[r2])[c] = s;
  }
  __syncthreads();
  {
    float y2 = x1 + stgA[rr][col];
    stgC[rr][col] = y2;
    __syncthreads();
    float s1 = 0.f, s2 = 0.f;
    #pragma unroll 8
    for (int c4 = 0; c4 < 32; ++c4) {
      float4 v = ((const float4*)stgC[rr])[c4];
      s1 += v.x + v.y + v.z + v.w;
      s2 += v.x*v.x + v.y*v.y + v.z*v.z + v.w*v.w;
    }
    float mu = s1 * (1.f / 128.f);
    float var = s2 * (1.f / 128.f) - mu * mu;
    if (q2 < 2)
      out[(size_t)(i0 + rr) * 128 + col] = (y2 - mu) * rsqrtf(var + 1e-5f) * ln2s[col] + ln2o[col];
  }
}

// ---------------- launch ----------------
extern "C" void kernel_launch(void* const* d_in, const int* in_sizes, int n_in,
                              void* d_out, int out_size, void* d_ws, size_t ws_size,
                              hipStream_t stream) {
  const float* Rg   = (const float*)d_in[0];
  const float* tg   = (const float*)d_in[1];
  const float* x    = (const float*)d_in[2];
  const float* z    = (const float*)d_in[3];
  // d_in[4] = mask (all true) -> no-op
  const float* Wq   = (const float*)d_in[5];
  const float* Wk   = (const float*)d_in[6];
  const float* Wpair= (const float*)d_in[7];
  const float* Wqp  = (const float*)d_in[8];
  const float* Wkp  = (const float*)d_in[9];
  const float* Wv   = (const float*)d_in[10];
  const float* Wvp  = (const float*)d_in[11];
  const float* sc   = (const float*)d_in[12];
  const float* Wo   = (const float*)d_in[13];
  const float* bo   = (const float*)d_in[14];
  const float* ln1s = (const float*)d_in[15];
  const float* ln1o = (const float*)d_in[16];
  const float* W1   = (const float*)d_in[17];
  const float* b1   = (const float*)d_in[18];
  const float* W2   = (const float*)d_in[19];
  const float* b2   = (const float*)d_in[20];
  const float* W3   = (const float*)d_in[21];
  const float* b3   = (const float*)d_in[22];
  const float* ln2s = (const float*)d_in[23];
  const float* ln2o = (const float*)d_in[24];

  float* ws = (float*)d_ws;
  float* proj   = ws;                        // 512*2016
  float* Ac     = proj + 512 * 2016;         // 344,064
  float* BcT    = Ac + 344064;               // 344,064
  float* Vc     = BcT + 344064;              // 344,064
  float* a2     = Vc + 344064;               // 6,144
  float* b2v    = a2 + 6144;                 // 6,144
  float* lgb    = b2v + 6144;                // 3,145,728
  float* alphab = lgb + 3145728;             // 3,145,728
  float* featb  = alphab + 3145728;          // 737,280

  k1_gemm  <<<168, 384, 0, stream>>>(x, Wq, Wk, Wqp, Wkp, Wv, Wvp, proj);
  k1b_prep <<<512, 256, 0, stream>>>(Rg, tg, sc, proj, Ac, BcT, Vc, a2, b2v);
  k2l_logits<<<384, 512, 0, stream>>>(Ac, BcT, a2, b2v, lgb);
  kz_fused <<<512, 512, 0, stream>>>(z, Wpair, lgb, alphab, featb);
  k3b_nodevp<<<384, 512, 0, stream>>>(alphab, Vc, Rg, tg, featb);
  k4_mlp   <<<256, 512, 0, stream>>>(featb, x, Wo, bo, ln1s, ln1o,
                                     W1, b1, W2, b2, W3, b3, ln2s, ln2o, (float*)d_out);
}

// Round 14
// 119.318 us; speedup vs baseline: 1.1586x; 1.1586x over previous
//
#include <hip/hip_runtime.h>

// N=1, L=512, F=128, C=64, H=12, QK=32, Vd=32, Pq=8, Pv=8
#define PCOLS 2016

constexpr float INV_SQRT_QK = 0.17677669529663687f;  // 1/sqrt(32)
constexpr float S3          = 0.57735026918962576f;  // sqrt(1/3)

#define FMA4(acc, s, b) { acc.x += (s)*(b).x; acc.y += (s)*(b).y; acc.z += (s)*(b).z; acc.w += (s)*(b).w; }
#define ADD4(acc, b)    { acc.x += (b).x; acc.y += (b).y; acc.z += (b).z; acc.w += (b).w; }

// ---------------- K1: all projections as one tiled GEMM (LDS-staged W) ----------------
__global__ __launch_bounds__(384) void k1_gemm(
    const float* __restrict__ x,
    const float* __restrict__ Wq, const float* __restrict__ Wk,
    const float* __restrict__ Wqp, const float* __restrict__ Wkp,
    const float* __restrict__ Wv, const float* __restrict__ Wvp,
    float* __restrict__ proj) {
  int bt = blockIdx.x;
  int it = bt / 21, ot = bt % 21;
  int i0 = it * 64;
  int tid = threadIdx.x;
  __shared__ float xs[64 * 128];
  __shared__ float ws[128 * 96];
  const float* Wsec; int lofs, width;
  if (ot < 4)       { Wsec = Wq;  lofs = ot * 96;        width = 384; }
  else if (ot < 8)  { Wsec = Wk;  lofs = (ot - 4) * 96;  width = 384; }
  else if (ot < 11) { Wsec = Wqp; lofs = (ot - 8) * 96;  width = 288; }
  else if (ot < 14) { Wsec = Wkp; lofs = (ot - 11) * 96; width = 288; }
  else if (ot < 18) { Wsec = Wv;  lofs = (ot - 14) * 96; width = 384; }
  else              { Wsec = Wvp; lofs = (ot - 18) * 96; width = 288; }
  for (int g = tid; g < 2048; g += 384)
    *(float4*)(xs + (g >> 5) * 128 + (g & 31) * 4) =
      *(const float4*)(x + (size_t)(i0 + (g >> 5)) * 128 + (g & 31) * 4);
  for (int g = tid; g < 3072; g += 384) {
    int r = g / 24, u = g % 24;
    *(float4*)(ws + r * 96 + u * 4) = *(const float4*)(Wsec + (size_t)r * width + lofs + u * 4);
  }
  __syncthreads();
  int cg = tid % 24, tr = tid / 24;
  float4 acc0 = {0,0,0,0}, acc1 = {0,0,0,0}, acc2 = {0,0,0,0}, acc3 = {0,0,0,0};
  const float* x0 = xs + (tr * 4 + 0) * 128;
  const float* x1 = xs + (tr * 4 + 1) * 128;
  const float* x2 = xs + (tr * 4 + 2) * 128;
  const float* x3 = xs + (tr * 4 + 3) * 128;
  #pragma unroll 4
  for (int k = 0; k < 128; ++k) {
    float4 w = *(const float4*)(ws + k * 96 + cg * 4);
    FMA4(acc0, x0[k], w); FMA4(acc1, x1[k], w);
    FMA4(acc2, x2[k], w); FMA4(acc3, x3[k], w);
  }
  int gc = ot * 96 + cg * 4;
  *(float4*)(proj + (size_t)(i0 + tr * 4 + 0) * PCOLS + gc) = acc0;
  *(float4*)(proj + (size_t)(i0 + tr * 4 + 1) * PCOLS + gc) = acc1;
  *(float4*)(proj + (size_t)(i0 + tr * 4 + 2) * PCOLS + gc) = acc2;
  *(float4*)(proj + (size_t)(i0 + tr * 4 + 3) * PCOLS + gc) = acc3;
}

// ---------------- K1b: l2g transform + compact operands Ac / BcT / Vc / a2 / b2 ----------------
__global__ __launch_bounds__(256) void k1b_prep(
    const float* __restrict__ Rg, const float* __restrict__ tg, const float* __restrict__ sc,
    const float* __restrict__ proj, float* __restrict__ Ac, float* __restrict__ BcT,
    float* __restrict__ Vc, float* __restrict__ a2, float* __restrict__ b2) {
  int j = blockIdx.x, tid = threadIdx.x;
  __shared__ float qk[1344];
  __shared__ float vls[384];
  __shared__ float vps[288], Rs[9], ts[3], cf[12];
  const float* pr = proj + (size_t)j * PCOLS;
  const float4* pr4 = (const float4*)pr;
  for (int g = tid; g < 336; g += 256) ((float4*)qk)[g] = pr4[g];
  for (int g = tid; g < 96; g += 256) ((float4*)vls)[g] = pr4[336 + g];
  for (int g = tid; g < 72; g += 256) ((float4*)vps)[g] = pr4[432 + g];
  if (tid < 9) Rs[tid] = Rg[j * 9 + tid];
  else if (tid < 12) ts[tid - 9] = tg[j * 3 + tid - 9];
  else if (tid < 24) cf[tid - 12] = -log1pf(__expf(sc[tid - 12])) * (1.0f / 12.0f);
  __syncthreads();
  for (int p = tid; p < 288; p += 256) {
    int sec = p / 96, m = p % 96;
    float* P = (sec == 0) ? qk + 768 : (sec == 1) ? qk + 1056 : vps;
    float* pp = P + m * 3;
    float p0 = pp[0], p1 = pp[1], p2 = pp[2];
    pp[0] = Rs[0]*p0 + Rs[1]*p1 + Rs[2]*p2 + ts[0];
    pp[1] = Rs[3]*p0 + Rs[4]*p1 + Rs[5]*p2 + ts[1];
    pp[2] = Rs[6]*p0 + Rs[7]*p1 + Rs[8]*p2 + ts[2];
  }
  __syncthreads();
  if (tid < 24) {
    int h = tid % 12;
    const float* s = (tid < 12) ? qk + 768 + h * 24 : qk + 1056 + h * 24;
    float a = 0.f;
    #pragma unroll
    for (int d = 0; d < 24; ++d) a += s[d] * s[d];
    float val = S3 * cf[h] * a;
    if (tid < 12) a2[h * 512 + j] = val; else b2[h * 512 + j] = val;
  }
  float s1 = S3 * INV_SQRT_QK;
  for (int o = tid; o < 672; o += 256) {
    int h = o / 56, d = o % 56;
    float s2 = -2.0f * S3 * cf[h];
    float aval = (d < 32) ? qk[h * 32 + d] * s1 : qk[768 + h * 24 + (d - 32)] * s2;
    float bval = (d < 32) ? qk[384 + h * 32 + d] : qk[1056 + h * 24 + (d - 32)];
    float vval = (d < 32) ? vls[h * 32 + d]      : vps[h * 24 + (d - 32)];
    Ac[((size_t)h * 512 + j) * 56 + d] = aval;
    BcT[((size_t)h * 56 + d) * 512 + j] = bval;
    Vc[((size_t)h * 512 + j) * 56 + d] = vval;
  }
}

// ---------------- K2l: node+spatial logits GEMM (K=56) -> lgb[h][i][j] ----------------
__global__ __launch_bounds__(512) void k2l_logits(
    const float* __restrict__ Ac, const float* __restrict__ BcT,
    const float* __restrict__ a2, const float* __restrict__ b2,
    float* __restrict__ lgb) {
  int blk = blockIdx.x;
  int h = blk >> 5, i0 = (blk & 31) * 16;
  int tid = threadIdx.x;
  __shared__ float At[16 * 60];
  __shared__ float BtT[56 * 132];
  __shared__ float b2s[512];
  __shared__ float a2s[16];
  for (int g = tid; g < 224; g += 512) {
    int row = g / 14, u = g % 14;
    *(float4*)(At + row * 60 + u * 4) =
      *(const float4*)(Ac + ((size_t)h * 512 + i0 + row) * 56 + u * 4);
  }
  if (tid < 128) ((float4*)b2s)[tid] = ((const float4*)(b2 + h * 512))[tid];
  if (tid >= 128 && tid < 144) a2s[tid - 128] = a2[h * 512 + i0 + tid - 128];
  int ti = tid >> 6, tj = tid & 63;
  int r0 = 2 * ti;
  const size_t lbase = (size_t)h * 262144;
  for (int jt = 0; jt < 4; ++jt) {
    int j0 = jt * 128;
    __syncthreads();
    for (int g = tid; g < 1792; g += 512) {
      int k = g >> 5, c4 = g & 31;
      *(float4*)(BtT + k * 132 + c4 * 4) =
        *(const float4*)(BcT + ((size_t)h * 56 + k) * 512 + j0 + c4 * 4);
    }
    __syncthreads();
    float a00 = 0.f, a01 = 0.f, a10 = 0.f, a11 = 0.f;
    const float* At0 = At + r0 * 60;
    #pragma unroll 8
    for (int k = 0; k < 56; ++k) {
      float a0 = At0[k], a1 = At0[60 + k];
      float2 b = *(const float2*)(BtT + k * 132 + 2 * tj);
      a00 += a0 * b.x; a01 += a0 * b.y;
      a10 += a1 * b.x; a11 += a1 * b.y;
    }
    int c0 = j0 + 2 * tj;
    float bb0 = b2s[c0], bb1 = b2s[c0 + 1];
    *(float2*)(lgb + lbase + (size_t)(i0 + r0) * 512 + c0) =
      make_float2(a00 + a2s[r0] + bb0, a01 + a2s[r0] + bb1);
    *(float2*)(lgb + lbase + (size_t)(i0 + r0 + 1) * 512 + c0) =
      make_float2(a10 + a2s[r0 + 1] + bb0, a11 + a2s[r0 + 1] + bb1);
  }
}

// ---------------- KZ v4: pair logits (broadcast-W, thread=row, no shfl) + softmax + p2n ----------------
// grid 512 (one i per block), 512 threads. Pass A: thread = j-row; z read direct from
// global (consumed once); Wpair read as wave-uniform b128 broadcast from 3 KB LDS
// (one DS instr per wave, amortized x64 lanes). Zero shfls, ~50 live VGPRs.
__global__ __launch_bounds__(512) void kz_fused(
    const float* __restrict__ z, const float* __restrict__ Wpair,
    const float* __restrict__ lgb,
    float* __restrict__ alphab, float* __restrict__ featb) {
  int i = blockIdx.x;
  int tid = threadIdx.x;
  int lane = tid & 63, wv = tid >> 6;
  __shared__ float lg[12 * 516];     // 24.8 KB: pair logits -> alpha
  __shared__ float zt[64 * 68];      // 17.4 KB (pass B only)
  __shared__ float wps[768];         // 3 KB: Wpair [c][h] as-is
  __shared__ float4 part[192];       // 3 KB (pass B)
  for (int g = tid; g < 192; g += 512) ((float4*)wps)[g] = ((const float4*)Wpair)[g];
  __syncthreads();
  // --- pass A: thread = row j = tid ---
  {
    float acc[12];
    #pragma unroll
    for (int h = 0; h < 12; ++h) acc[h] = 0.f;
    const float4* zr = (const float4*)(z + ((size_t)i * 512 + tid) * 64);
    #pragma unroll
    for (int ch = 0; ch < 4; ++ch) {
      float4 zv0 = zr[ch * 4 + 0], zv1 = zr[ch * 4 + 1];
      float4 zv2 = zr[ch * 4 + 2], zv3 = zr[ch * 4 + 3];
      float zc[16] = {zv0.x, zv0.y, zv0.z, zv0.w, zv1.x, zv1.y, zv1.z, zv1.w,
                      zv2.x, zv2.y, zv2.z, zv2.w, zv3.x, zv3.y, zv3.z, zv3.w};
      #pragma unroll
      for (int cc = 0; cc < 16; ++cc) {
        float zz = zc[cc];
        const float* wr = wps + (ch * 16 + cc) * 12;   // 48B-aligned
        float4 w0 = *(const float4*)(wr);
        float4 w1 = *(const float4*)(wr + 4);
        float4 w2 = *(const float4*)(wr + 8);
        acc[0] += zz * w0.x; acc[1] += zz * w0.y; acc[2]  += zz * w0.z; acc[3]  += zz * w0.w;
        acc[4] += zz * w1.x; acc[5] += zz * w1.y; acc[6]  += zz * w1.z; acc[7]  += zz * w1.w;
        acc[8] += zz * w2.x; acc[9] += zz * w2.y; acc[10] += zz * w2.z; acc[11] += zz * w2.w;
      }
    }
    #pragma unroll
    for (int h = 0; h < 12; ++h) lg[h * 516 + tid] = acc[h] * S3;
  }
  __syncthreads();
  // --- softmax per head (wave-parallel), fusing lgb add; alpha -> LDS + global ---
  for (int h = wv; h < 12; h += 8) {
    const float* lr = lgb + (size_t)h * 262144 + (size_t)i * 512;
    float v[8];
    float m = -1e30f;
    #pragma unroll
    for (int u = 0; u < 8; ++u) {
      v[u] = lg[h * 516 + u * 64 + lane] + lr[u * 64 + lane];
      m = fmaxf(m, v[u]);
    }
    #pragma unroll
    for (int s = 32; s > 0; s >>= 1) m = fmaxf(m, __shfl_xor(m, s));
    float ssum = 0.f;
    #pragma unroll
    for (int u = 0; u < 8; ++u) { v[u] = __expf(v[u] - m); ssum += v[u]; }
    #pragma unroll
    for (int s = 32; s > 0; s >>= 1) ssum += __shfl_xor(ssum, s);
    float inv = 1.0f / ssum;
    float* ar = alphab + (size_t)h * 262144 + (size_t)i * 512;
    #pragma unroll
    for (int u = 0; u < 8; ++u) {
      float a = v[u] * inv;
      lg[h * 516 + u * 64 + lane] = a;
      ar[u * 64 + lane] = a;
    }
  }
  __syncthreads();
  // --- pass B: feat_p2n = alpha @ z[i], z re-read (L2/L3-hot), k-split 2 ---
  int h3 = tid >> 5, c4 = (tid & 31) >> 1, ks = tid & 1;   // valid tid < 384
  float4 acc4 = {0, 0, 0, 0};
  for (int it = 0; it < 8; ++it) {
    __syncthreads();
    for (int g = tid; g < 1024; g += 512) {
      int row = g >> 4, cc = g & 15;
      *(float4*)(zt + row * 68 + cc * 4) =
        *(const float4*)(z + ((size_t)i * 512 + it * 64 + row) * 64 + cc * 4);
    }
    __syncthreads();
    if (tid < 384) {
      const float* ar2 = lg + h3 * 516 + it * 64 + ks * 32;
      const float* zb = zt + (ks * 32) * 68 + c4 * 4;
      #pragma unroll
      for (int kk = 0; kk < 32; kk += 4) {
        float4 a4 = *(const float4*)(ar2 + kk);
        float4 b0 = *(const float4*)(zb + (kk + 0) * 68);
        float4 b1 = *(const float4*)(zb + (kk + 1) * 68);
        float4 b2v = *(const float4*)(zb + (kk + 2) * 68);
        float4 b3 = *(const float4*)(zb + (kk + 3) * 68);
        FMA4(acc4, a4.x, b0); FMA4(acc4, a4.y, b1);
        FMA4(acc4, a4.z, b2v); FMA4(acc4, a4.w, b3);
      }
    }
  }
  __syncthreads();
  if (tid < 384 && ks == 1) part[h3 * 16 + c4] = acc4;
  __syncthreads();
  if (tid < 384 && ks == 0) {
    float4 s = part[h3 * 16 + c4];
    ADD4(acc4, s);
    *(float4*)(featb + (size_t)i * 1440 + h3 * 64 + c4 * 4) = acc4;
  }
}

// ---------------- K3b: node/vp aggregation + g2l (alpha from global, compact Vc) ----------------
__global__ __launch_bounds__(512) void k3b_nodevp(
    const float* __restrict__ alphab, const float* __restrict__ Vc,
    const float* __restrict__ Rg, const float* __restrict__ tg,
    float* __restrict__ featb) {
  int blk = blockIdx.x;
  int h = blk >> 5, i0 = (blk & 31) * 16;
  int tid = threadIdx.x;
  __shared__ float als[16 * 516];
  __shared__ float Bt2[2 * 64 * 60];
  __shared__ float4 part4[448];
  __shared__ float ag[16 * 24];
  for (int g = tid; g < 2048; g += 512) {
    int row = g >> 7, c4 = g & 127;
    *(float4*)(als + row * 516 + c4 * 4) =
      *(const float4*)(alphab + (size_t)h * 262144 + (size_t)(i0 + row) * 512 + c4 * 4);
  }
  int half = tid / 224, rem = tid % 224;
  int rg = rem / 14, cgp = rem % 14;
  int c0p = cgp * 4;
  float4 acc4 = {0, 0, 0, 0};
  for (int tt = 0; tt < 4; ++tt) {
    __syncthreads();
    for (int g = tid; g < 1792; g += 512) {
      int hh = g / 896, gg = g % 896;
      int row = gg / 14, u = gg % 14;
      *(float4*)(Bt2 + hh * 3840 + row * 60 + u * 4) =
        *(const float4*)(Vc + ((size_t)h * 512 + (tt + 4 * hh) * 64 + row) * 56 + u * 4);
    }
    __syncthreads();
    if (tid < 448) {
      const float* arow = als + rg * 516 + (tt + 4 * half) * 64;
      const float* bt = Bt2 + half * 3840;
      #pragma unroll 8
      for (int kk = 0; kk < 64; ++kk) {
        float a = arow[kk];
        float4 b = *(const float4*)(bt + kk * 60 + c0p);
        FMA4(acc4, a, b);
      }
    }
  }
  __syncthreads();
  if (tid < 448) part4[half * 224 + rg * 14 + cgp] = acc4;
  __syncthreads();
  if (tid < 224) {
    float4 s = part4[rem];
    float4 s2 = part4[224 + rem];
    ADD4(s, s2);
    if (c0p < 32) {
      *(float4*)(&featb[(size_t)(i0 + rg) * 1440 + 768 + h * 32 + c0p]) = s;
    } else {
      int cc = c0p - 32;
      ag[rg * 24 + cc + 0] = s.x; ag[rg * 24 + cc + 1] = s.y;
      ag[rg * 24 + cc + 2] = s.z; ag[rg * 24 + cc + 3] = s.w;
    }
  }
  __syncthreads();
  if (tid < 128) {
    int row = tid >> 3, p = tid & 7;
    const float* R  = Rg + (size_t)(i0 + row) * 9;
    const float* tt = tg + (size_t)(i0 + row) * 3;
    float d0 = ag[row * 24 + p * 3 + 0] - tt[0];
    float d1 = ag[row * 24 + p * 3 + 1] - tt[1];
    float d2 = ag[row * 24 + p * 3 + 2] - tt[2];
    float* oo = featb + (size_t)(i0 + row) * 1440 + 1152 + h * 24 + p * 3;
    oo[0] = R[0]*d0 + R[3]*d1 + R[6]*d2;
    oo[1] = R[1]*d0 + R[4]*d1 + R[7]*d2;
    oo[2] = R[2]*d0 + R[5]*d1 + R[8]*d2;
  }
}

// ---------------- K4: Wo GEMM + LN1 + MLP + LN2 ----------------
__global__ __launch_bounds__(512) void k4_mlp(
    const float* __restrict__ featb, const float* __restrict__ x,
    const float* __restrict__ Wo, const float* __restrict__ bo,
    const float* __restrict__ ln1s, const float* __restrict__ ln1o,
    const float* __restrict__ W1, const float* __restrict__ b1,
    const float* __restrict__ W2, const float* __restrict__ b2,
    const float* __restrict__ W3, const float* __restrict__ b3,
    const float* __restrict__ ln2s, const float* __restrict__ ln2o,
    float* __restrict__ out) {
  int i0 = blockIdx.x * 2;
  int tid = threadIdx.x;
  __shared__ float fs[2 * 1440];
  __shared__ float4 part4[16][2][32];
  __shared__ float stgA[2][128], stgB[2][128], stgC[2][128];
  for (int g = tid; g < 720; g += 512)
    ((float4*)fs)[g] = ((const float4*)(featb + (size_t)i0 * 1440))[g];
  __syncthreads();
  int q = tid >> 5, cg = tid & 31;
  {
    float4 a0 = {0,0,0,0}, a1 = {0,0,0,0};
    int cb = q * 90;
    const float* f0 = fs + cb, *f1 = fs + 1440 + cb;
    #pragma unroll 6
    for (int c = 0; c < 90; ++c) {
      float4 w = *((const float4*)(Wo + (size_t)(cb + c) * 128) + cg);
      FMA4(a0, f0[c], w);
      FMA4(a1, f1[c], w);
    }
    part4[q][0][cg] = a0;
    part4[q][1][cg] = a1;
  }
  __syncthreads();
  if (tid < 64) {
    int rr = tid >> 5, c = tid & 31;
    float4 s = part4[0][rr][c];
    #pragma unroll
    for (int k = 1; k < 16; ++k) ADD4(s, part4[k][rr][c]);
    float4 bo4 = ((const float4*)bo)[c];
    float4 xr4 = ((const float4*)(x + (size_t)(i0 + rr) * 128))[c];
    s.x += bo4.x + xr4.x; s.y += bo4.y + xr4.y; s.z += bo4.z + xr4.z; s.w += bo4.w + xr4.w;
    ((float4*)stgA[rr])[c] = s;
  }
  __syncthreads();
  int q2 = tid >> 7, col = tid & 127, rr = q2 & 1;
  float x1;
  {
    float y = stgA[rr][col];
    float s1 = 0.f, s2 = 0.f;
    #pragma unroll 8
    for (int c4 = 0; c4 < 32; ++c4) {
      float4 v = ((const float4*)stgA[rr])[c4];
      s1 += v.x + v.y + v.z + v.w;
      s2 += v.x*v.x + v.y*v.y + v.z*v.z + v.w*v.w;
    }
    float mu = s1 * (1.f / 128.f);
    float var = s2 * (1.f / 128.f) - mu * mu;
    x1 = (y - mu) * rsqrtf(var + 1e-5f) * ln1s[col] + ln1o[col];
  }
  __syncthreads();
  stgB[rr][col] = x1;
  __syncthreads();
  int sub = tid >> 5, rr1 = sub & 1, kq = sub >> 1;
  {
    float4 aa = {0,0,0,0};
    int c0 = kq * 16;
    #pragma unroll
    for (int c = 0; c < 16; ++c) {
      float4 w = *((const float4*)(W1 + (size_t)(c0 + c) * 128) + cg);
      FMA4(aa, stgB[rr1][c0 + c], w);
    }
    part4[sub][0][cg] = aa;
  }
  __syncthreads();
  if (tid < 64) {
    int r2 = tid >> 5, c = tid & 31;
    float4 s = part4[r2][0][c];
    #pragma unroll
    for (int k = 1; k < 8; ++k) ADD4(s, part4[k * 2 + r2][0][c]);
    float4 b4 = ((const float4*)b1)[c];
    s.x = fmaxf(s.x + b4.x, 0.f); s.y = fmaxf(s.y + b4.y, 0.f);
    s.z = fmaxf(s.z + b4.z, 0.f); s.w = fmaxf(s.w + b4.w, 0.f);
    ((float4*)stgA[r2])[c] = s;
  }
  __syncthreads();
  {
    float4 aa = {0,0,0,0};
    int c0 = kq * 16;
    #pragma unroll
    for (int c = 0; c < 16; ++c) {
      float4 w = *((const float4*)(W2 + (size_t)(c0 + c) * 128) + cg);
      FMA4(aa, stgA[rr1][c0 + c], w);
    }
    part4[sub][0][cg] = aa;
  }
  __syncthreads();
  if (tid < 64) {
    int r2 = tid >> 5, c = tid & 31;
    float4 s = part4[r2][0][c];
    #pragma unroll
    for (int k = 1; k < 8; ++k) ADD4(s, part4[k * 2 + r2][0][c]);
    float4 b4 = ((const float4*)b2)[c];
    s.x = fmaxf(s.x + b4.x, 0.f); s.y = fmaxf(s.y + b4.y, 0.f);
    s.z = fmaxf(s.z + b4.z, 0.f); s.w = fmaxf(s.w + b4.w, 0.f);
    ((float4*)stgC[r2])[c] = s;
  }
  __syncthreads();
  {
    float4 aa = {0,0,0,0};
    int c0 = kq * 16;
    #pragma unroll
    for (int c = 0; c < 16; ++c) {
      float4 w = *((const float4*)(W3 + (size_t)(c0 + c) * 128) + cg);
      FMA4(aa, stgC[rr1][c0 + c], w);
    }
    part4[sub][0][cg] = aa;
  }
  __syncthreads();
  if (tid < 64) {
    int r2 = tid >> 5, c = tid & 31;
    float4 s = part4[r2][0][c];
    #pragma unroll
    for (int k = 1; k < 8; ++k) ADD4(s, part4[k * 2 + r2][0][c]);
    float4 b4 = ((const float4*)b3)[c];
    s.x += b4.x; s.y += b4.y; s.z += b4.z; s.w += b4.w;
    ((float4*)stgA[r2])[c] = s;
  }
  __syncthreads();
  {
    float y2 = x1 + stgA[rr][col];
    stgC[rr][col] = y2;
    __syncthreads();
    float s1 = 0.f, s2 = 0.f;
    #pragma unroll 8
    for (int c4 = 0; c4 < 32; ++c4) {
      float4 v = ((const float4*)stgC[rr])[c4];
      s1 += v.x + v.y + v.z + v.w;
      s2 += v.x*v.x + v.y*v.y + v.z*v.z + v.w*v.w;
    }
    float mu = s1 * (1.f / 128.f);
    float var = s2 * (1.f / 128.f) - mu * mu;
    if (q2 < 2)
      out[(size_t)(i0 + rr) * 128 + col] = (y2 - mu) * rsqrtf(var + 1e-5f) * ln2s[col] + ln2o[col];
  }
}

// ---------------- launch ----------------
extern "C" void kernel_launch(void* const* d_in, const int* in_sizes, int n_in,
                              void* d_out, int out_size, void* d_ws, size_t ws_size,
                              hipStream_t stream) {
  const float* Rg   = (const float*)d_in[0];
  const float* tg   = (const float*)d_in[1];
  const float* x    = (const float*)d_in[2];
  const float* z    = (const float*)d_in[3];
  // d_in[4] = mask (all true) -> no-op
  const float* Wq   = (const float*)d_in[5];
  const float* Wk   = (const float*)d_in[6];
  const float* Wpair= (const float*)d_in[7];
  const float* Wqp  = (const float*)d_in[8];
  const float* Wkp  = (const float*)d_in[9];
  const float* Wv   = (const float*)d_in[10];
  const float* Wvp  = (const float*)d_in[11];
  const float* sc   = (const float*)d_in[12];
  const float* Wo   = (const float*)d_in[13];
  const float* bo   = (const float*)d_in[14];
  const float* ln1s = (const float*)d_in[15];
  const float* ln1o = (const float*)d_in[16];
  const float* W1   = (const float*)d_in[17];
  const float* b1   = (const float*)d_in[18];
  const float* W2   = (const float*)d_in[19];
  const float* b2   = (const float*)d_in[20];
  const float* W3   = (const float*)d_in[21];
  const float* b3   = (const float*)d_in[22];
  const float* ln2s = (const float*)d_in[23];
  const float* ln2o = (const float*)d_in[24];

  float* ws = (float*)d_ws;
  float* proj   = ws;                        // 512*2016
  float* Ac     = proj + 512 * 2016;         // 344,064
  float* BcT    = Ac + 344064;               // 344,064
  float* Vc     = BcT + 344064;              // 344,064
  float* a2     = Vc + 344064;               // 6,144
  float* b2v    = a2 + 6144;                 // 6,144
  float* lgb    = b2v + 6144;                // 3,145,728
  float* alphab = lgb + 3145728;             // 3,145,728
  float* featb  = alphab + 3145728;          // 737,280

  k1_gemm  <<<168, 384, 0, stream>>>(x, Wq, Wk, Wqp, Wkp, Wv, Wvp, proj);
  k1b_prep <<<512, 256, 0, stream>>>(Rg, tg, sc, proj, Ac, BcT, Vc, a2, b2v);
  k2l_logits<<<384, 512, 0, stream>>>(Ac, BcT, a2, b2v, lgb);
  kz_fused <<<512, 512, 0, stream>>>(z, Wpair, lgb, alphab, featb);
  k3b_nodevp<<<384, 512, 0, stream>>>(alphab, Vc, Rg, tg, featb);
  k4_mlp   <<<256, 512, 0, stream>>>(featb, x, Wo, bo, ln1s, ln1o,
                                     W1, b1, W2, b2, W3, b3, ln2s, ln2o, (float*)d_out);
}